// Round 8
// baseline (468.311 us; speedup 1.0000x reference)
//
#include <hip/hip_runtime.h>
#include <math.h>

typedef short short8 __attribute__((ext_vector_type(8)));
typedef float f32x4 __attribute__((ext_vector_type(4)));

#define B_    2
#define HH    128
#define WW    128
#define NPIX  16384     // H*W
#define C_    384
#define CR    192
#define CG    128
#define NH    8
#define DK    24
#define HD    48
#define LL    1024      // 32*32 reduced tokens
#define KFUS  6144      // 16*384
// (hd*0.5)^-0.5 * log2(e)  — folded so P = exp2(S)
#define SCALE_L2E 0.29448889f

__device__ __forceinline__ float bf2f(short h) {
    union { unsigned u; float f; } v; v.u = ((unsigned)(unsigned short)h) << 16; return v.f;
}
__device__ __forceinline__ short f2bf(float f) {          // RNE
    union { float f; unsigned u; } v; v.f = f;
    unsigned r = v.u + 0x7fffu + ((v.u >> 16) & 1u);
    return (short)(unsigned short)(r >> 16);
}
__device__ __forceinline__ short f2bf_fast(float f) {     // round-nearest, ties-away
    union { float f; unsigned u; } v; v.f = f;
    return (short)(unsigned short)((v.u + 0x8000u) >> 16);
}
// pack bf16(a) (low) | bf16(b) (high), ties-away rounding — pure C
__device__ __forceinline__ unsigned pack2(float a, float b) {
    union { float f; unsigned u; } x, y; x.f = a; y.f = b;
    return ((x.u + 0x8000u) >> 16) | ((y.u + 0x8000u) & 0xFFFF0000u);
}

// ---------------------------------------------------------------------------
// Depthwise conv, one 128-channel group, 4 x-pixels per thread (x0 % 4 == 0).
// PATCH=0: fp32 flat out [B,NPIX,128].
// PATCH=1: bf16 im2col patch layout for the 4x4/stride4 conv.
// ---------------------------------------------------------------------------
template<int PATCH, int KS, int STRIDE>
__global__ __launch_bounds__(256) void dwconv_k(
    const float* __restrict__ in, int in_off,
    float* __restrict__ outf, short* __restrict__ outp, int out_coff,
    const float* __restrict__ w, const float* __restrict__ bias)
{
    constexpr int pad = KS / 2;
    constexpr int NV = 4 + KS - 1;
    int idx = blockIdx.x * 256 + threadIdx.x;   // 2*4096*128 total
    int c    = idx & (CG - 1);
    int pix4 = (idx >> 7) & 4095;
    int b    = idx >> 19;
    int y = pix4 >> 5, x0 = (pix4 & 31) << 2;
    float wl[KS * KS];
    #pragma unroll
    for (int i = 0; i < KS * KS; i++) wl[i] = w[c * KS * KS + i];
    float bv = bias[c];
    float acc[4] = {bv, bv, bv, bv};
    #pragma unroll
    for (int ky = 0; ky < KS; ky++) {
        int yy = y + ky - pad;
        if ((unsigned)yy >= HH) continue;
        const float* rowp = &in[(size_t)(b * NPIX + yy * WW) * STRIDE + in_off + c];
        float v[NV];
        #pragma unroll
        for (int j = 0; j < NV; j++) {
            int xx = x0 + j - pad;
            v[j] = ((unsigned)xx < WW) ? rowp[(size_t)xx * STRIDE] : 0.f;
        }
        #pragma unroll
        for (int kx = 0; kx < KS; kx++)
            #pragma unroll
            for (int o = 0; o < 4; o++)
                acc[o] += v[o + kx] * wl[ky * KS + kx];
    }
    if (!PATCH) {
        float* op = &outf[(size_t)(b * NPIX + y * WW + x0) * CG + c];
        #pragma unroll
        for (int o = 0; o < 4; o++) op[(size_t)o * CG] = acc[o];
    } else {
        int m = b * LL + (y >> 2) * 32 + (x0 >> 2);
        short* op = &outp[(size_t)m * KFUS + ((y & 3) * 4) * C_ + out_coff + c];
        #pragma unroll
        for (int o = 0; o < 4; o++) op[(size_t)o * C_] = f2bf(acc[o]);
    }
}

// ---------------------------------------------------------------------------
// Weight prep (fp32 -> bf16)
// ---------------------------------------------------------------------------
__global__ __launch_bounds__(256) void prep_k(
    const float* __restrict__ fus_w, const float* __restrict__ k_w,
    const float* __restrict__ v_w, const float* __restrict__ q_w,
    const float* __restrict__ proj_w,
    short* __restrict__ Wt, short* __restrict__ Bkv,
    short* __restrict__ qw_b, short* __restrict__ pw_b)
{
    int idx = blockIdx.x * 256 + threadIdx.x;
    const int NW = KFUS * CR;        // 1179648
    if (idx < NW) {
        int k = idx / CR, oc = idx - k * CR;
        int p = k / C_,  ic = k - p * C_;
        Wt[idx] = f2bf(fus_w[(oc * C_ + ic) * 16 + p]);
        return;
    }
    idx -= NW;
    if (idx < CR * 576) {            // 110592
        int k = idx / 576, n = idx - k * 576;
        Bkv[idx] = f2bf((n < CR) ? k_w[k * CR + n] : v_w[k * C_ + (n - CR)]);
        return;
    }
    idx -= CR * 576;
    if (idx < C_ * CR) { qw_b[idx] = f2bf(q_w[idx]); return; }
    idx -= C_ * CR;
    if (idx < C_ * C_) pw_b[idx] = f2bf(proj_w[idx]);
}

// ---------------------------------------------------------------------------
// Generic bf16 MFMA GEMM: C[M,N] = A[M,K] * B[K,N] (+bias)
// AF=1: A fp32 (converted on stage). CF=1: C written fp32.
// ---------------------------------------------------------------------------
template<int AF, int CF>
__global__ __launch_bounds__(256) void gemm_k(
    const void* __restrict__ Av, const short* __restrict__ Bm, void* __restrict__ Cv,
    const float* __restrict__ bias, int M, int N, int K)
{
    __shared__ short a_lds[64 * 40];
    __shared__ short bT_lds[64 * 40];
    int tid = threadIdx.x;
    int lane = tid & 63, wave = tid >> 6, quad = lane >> 4, l16 = lane & 15;
    int bm = blockIdx.x * 64, bn = blockIdx.y * 64;
    int wm = (wave >> 1) * 32, wn = (wave & 1) * 32;
    f32x4 z4 = {0.f, 0.f, 0.f, 0.f};
    f32x4 acc00 = z4, acc01 = z4, acc10 = z4, acc11 = z4;
    int arow = tid >> 2, aseg = tid & 3;
    int bk = tid >> 3, bnseg = tid & 7;

    for (int k0 = 0; k0 < K; k0 += 32) {
        __syncthreads();
        if (AF) {
            const float* Af = (const float*)Av;
            const float4* p = (const float4*)&Af[(size_t)(bm + arow) * K + k0 + aseg * 8];
            float4 f0 = p[0], f1 = p[1];
            short8 av;
            av[0] = f2bf_fast(f0.x); av[1] = f2bf_fast(f0.y);
            av[2] = f2bf_fast(f0.z); av[3] = f2bf_fast(f0.w);
            av[4] = f2bf_fast(f1.x); av[5] = f2bf_fast(f1.y);
            av[6] = f2bf_fast(f1.z); av[7] = f2bf_fast(f1.w);
            *(short8*)&a_lds[arow * 40 + aseg * 8] = av;
        } else {
            const short* Ab = (const short*)Av;
            *(short8*)&a_lds[arow * 40 + aseg * 8] =
                *(const short8*)&Ab[(size_t)(bm + arow) * K + k0 + aseg * 8];
        }
        short8 bv = *(const short8*)&Bm[(size_t)(k0 + bk) * N + bn + bnseg * 8];
        #pragma unroll
        for (int i = 0; i < 8; i++) bT_lds[(bnseg * 8 + i) * 40 + bk] = bv[i];
        __syncthreads();
        short8 a0 = *(short8*)&a_lds[(wm + l16) * 40 + quad * 8];
        short8 a1 = *(short8*)&a_lds[(wm + 16 + l16) * 40 + quad * 8];
        short8 b0 = *(short8*)&bT_lds[(wn + l16) * 40 + quad * 8];
        short8 b1 = *(short8*)&bT_lds[(wn + 16 + l16) * 40 + quad * 8];
        acc00 = __builtin_amdgcn_mfma_f32_16x16x32_bf16(a0, b0, acc00, 0, 0, 0);
        acc01 = __builtin_amdgcn_mfma_f32_16x16x32_bf16(a0, b1, acc01, 0, 0, 0);
        acc10 = __builtin_amdgcn_mfma_f32_16x16x32_bf16(a1, b0, acc10, 0, 0, 0);
        acc11 = __builtin_amdgcn_mfma_f32_16x16x32_bf16(a1, b1, acc11, 0, 0, 0);
    }
    f32x4 accs[2][2] = {{acc00, acc01}, {acc10, acc11}};
    #pragma unroll
    for (int mt = 0; mt < 2; mt++)
      #pragma unroll
      for (int nt = 0; nt < 2; nt++) {
        int col = bn + wn + nt * 16 + l16;
        float bvv = bias ? bias[col] : 0.f;
        #pragma unroll
        for (int r = 0; r < 4; r++) {
            int row = bm + wm + mt * 16 + quad * 4 + r;
            float v = accs[mt][nt][r] + bvv;
            if (CF) ((float*)Cv)[(size_t)row * N + col] = v;
            else    ((short*)Cv)[(size_t)row * N + col] = f2bf(v);
        }
      }
}

// ---------------------------------------------------------------------------
// Split-K GEMM for the fusion conv: fp32 partials per z-slice.
// ---------------------------------------------------------------------------
__global__ __launch_bounds__(256) void gemm_part_k(
    const short* __restrict__ A, const short* __restrict__ Bm,
    float* __restrict__ Cpart, int M, int N, int K, int kchunk)
{
    __shared__ short a_lds[64 * 40];
    __shared__ short bT_lds[64 * 40];
    int tid = threadIdx.x;
    int lane = tid & 63, wave = tid >> 6, quad = lane >> 4, l16 = lane & 15;
    int bm = blockIdx.x * 64, bn = blockIdx.y * 64;
    int kbeg = blockIdx.z * kchunk, kend = kbeg + kchunk;
    int wm = (wave >> 1) * 32, wn = (wave & 1) * 32;
    f32x4 z4 = {0.f, 0.f, 0.f, 0.f};
    f32x4 acc00 = z4, acc01 = z4, acc10 = z4, acc11 = z4;
    int arow = tid >> 2, aseg = tid & 3;
    int bk = tid >> 3, bnseg = tid & 7;

    for (int k0 = kbeg; k0 < kend; k0 += 32) {
        __syncthreads();
        *(short8*)&a_lds[arow * 40 + aseg * 8] =
            *(const short8*)&A[(size_t)(bm + arow) * K + k0 + aseg * 8];
        short8 bv = *(const short8*)&Bm[(size_t)(k0 + bk) * N + bn + bnseg * 8];
        #pragma unroll
        for (int i = 0; i < 8; i++) bT_lds[(bnseg * 8 + i) * 40 + bk] = bv[i];
        __syncthreads();
        short8 a0 = *(short8*)&a_lds[(wm + l16) * 40 + quad * 8];
        short8 a1 = *(short8*)&a_lds[(wm + 16 + l16) * 40 + quad * 8];
        short8 b0 = *(short8*)&bT_lds[(wn + l16) * 40 + quad * 8];
        short8 b1 = *(short8*)&bT_lds[(wn + 16 + l16) * 40 + quad * 8];
        acc00 = __builtin_amdgcn_mfma_f32_16x16x32_bf16(a0, b0, acc00, 0, 0, 0);
        acc01 = __builtin_amdgcn_mfma_f32_16x16x32_bf16(a0, b1, acc01, 0, 0, 0);
        acc10 = __builtin_amdgcn_mfma_f32_16x16x32_bf16(a1, b0, acc10, 0, 0, 0);
        acc11 = __builtin_amdgcn_mfma_f32_16x16x32_bf16(a1, b1, acc11, 0, 0, 0);
    }
    float* Cs = Cpart + (size_t)blockIdx.z * M * N;
    f32x4 accs[2][2] = {{acc00, acc01}, {acc10, acc11}};
    #pragma unroll
    for (int mt = 0; mt < 2; mt++)
      #pragma unroll
      for (int nt = 0; nt < 2; nt++) {
        int col = bn + wn + nt * 16 + l16;
        #pragma unroll
        for (int r = 0; r < 4; r++) {
            int row = bm + wm + mt * 16 + quad * 4 + r;
            Cs[(size_t)row * N + col] = accs[mt][nt][r];
        }
      }
}

// Reduce 4 split-K partials + bias + exact GELU -> bf16 xr [2048 x 192]
__global__ __launch_bounds__(256) void fusred_k(
    const float* __restrict__ part, const float* __restrict__ bias,
    short* __restrict__ xr)
{
    const int MN = 2048 * CR;
    int idx = blockIdx.x * 256 + threadIdx.x;
    float v = part[idx] + part[idx + MN] + part[idx + 2 * MN] + part[idx + 3 * MN]
            + bias[idx % CR];
    v = 0.5f * v * (1.f + erff(v * 0.70710678118f));
    xr[idx] = f2bf(v);
}

// ---------------------------------------------------------------------------
// CPE: v2[b,l,c] = v[b,l,c] + dwconv3x3(v as [B,C,32,32])[b,c,l] + cpe_b[c]
// ---------------------------------------------------------------------------
__global__ __launch_bounds__(256) void cpe_k(
    const short* __restrict__ kv, const float* __restrict__ cw,
    const float* __restrict__ cb, short* __restrict__ v2)
{
    int idx = blockIdx.x * 256 + threadIdx.x;   // 2*1024*384
    int c = idx % C_;
    int t = idx / C_;
    int l = t & (LL - 1);
    int b = t >> 10;
    int y = l >> 5, x = l & 31;
    const short* vp = kv + CR;
    float acc = bf2f(vp[(size_t)(b * LL + l) * 576 + c]) + cb[c];
    #pragma unroll
    for (int ky = 0; ky < 3; ky++) {
        int yy = y + ky - 1; if ((unsigned)yy >= 32) continue;
        #pragma unroll
        for (int kx = 0; kx < 3; kx++) {
            int xx = x + kx - 1; if ((unsigned)xx >= 32) continue;
            acc += bf2f(vp[(size_t)(b * LL + yy * 32 + xx) * 576 + c])
                 * cw[c * 9 + ky * 3 + kx];
        }
    }
    v2[(size_t)(b * LL + l) * C_ + c] = f2bf(acc);
}

// ---------------------------------------------------------------------------
// Build attention-friendly layouts:
//   v2t[bh][f 0..47][l 0..1023]  (transposed V, per head)
//   kpack[bh][l][j 0..31]        (K zero-padded dk24->32)
// ---------------------------------------------------------------------------
__global__ __launch_bounds__(256) void transp_k(
    const short* __restrict__ v2b, const short* __restrict__ kvb,
    short* __restrict__ v2t, short* __restrict__ kpack)
{
    int tid = threadIdx.x;
    if (blockIdx.x < 256) {
        __shared__ short t_lds[64 * 49];
        int bh = blockIdx.x >> 4, b = bh >> 3, h = bh & 7;
        int l0 = (blockIdx.x & 15) << 6;
        for (int i = tid; i < 64 * 48; i += 256) {
            int dl = i / 48, f = i - dl * 48;
            t_lds[dl * 49 + f] = v2b[(size_t)(b * LL + l0 + dl) * C_ + h * HD + f];
        }
        __syncthreads();
        for (int i = tid; i < 64 * 48; i += 256) {
            int f = i >> 6, dl = i & 63;
            v2t[((size_t)bh * 48 + f) * LL + l0 + dl] = t_lds[dl * 49 + f];
        }
    } else {
        int gid = (blockIdx.x - 256) * 256 + tid;   // 16*1024*32
        int j = gid & 31, t = gid >> 5;
        int l = t & (LL - 1), bh = t >> 10;
        int b = bh >> 3, h = bh & 7;
        kpack[gid] = (j < 24) ? kvb[(size_t)(b * LL + l) * 576 + h * DK + j] : (short)0;
    }
}

// ---------------------------------------------------------------------------
// Flash attention v4 (v3 fixed): S^T = K*Q^T so P is written as packed b64;
// V pre-transposed globally (v2t); K pre-padded (kpack); 32 queries/wave,
// 128 queries/block; row-sums via ones-feature MFMA; no-max exp2 softmax.
// Staging arithmetic is in SHORTS (short8 = 8 shorts): K = 2 short8/thread
// (4096 shorts/chunk), V = 3 short8/thread (6144 shorts/chunk) — full cover.
// ---------------------------------------------------------------------------
__global__ __launch_bounds__(256) void attn_k(
    const short* __restrict__ qbuf, const short* __restrict__ kpack,
    const short* __restrict__ v2t, short* __restrict__ obuf)
{
    __shared__ short k_lds[128 * 40];        // [key][k 0..31 valid, 8 pad]
    __shared__ short vT_lds[64 * 136];       // [feat][key]; rows 48..63 const
    __shared__ unsigned p_lds[4][32 * 68];   // per-wave [query][key/2] bf16x2
    int tid = threadIdx.x;
    int lane = tid & 63, wave = tid >> 6, quad = lane >> 4, l16 = lane & 15;
    int bh = blockIdx.y, b = bh >> 3, h = bh & 7;
    int q0 = blockIdx.x * 128 + wave * 32;

    // const rows: feature 48 = ones (row sums), 49..63 = zero
    for (int i = tid; i < 16 * 136; i += 256)
        vT_lds[48 * 136 + i] = (i < 128) ? (short)0x3F80 : (short)0;

    // Q fragments (2 x 16 queries), pre-scaled by scale*log2(e); k>=24 zero.
    short8 qf[2];
    #pragma unroll
    for (int qt = 0; qt < 2; qt++) {
        short8 z = {0, 0, 0, 0, 0, 0, 0, 0};
        qf[qt] = z;
        if (quad < 3) {
            short8 raw = *(const short8*)&qbuf[(size_t)(b * NPIX + q0 + qt * 16 + l16) * CR + h * DK + quad * 8];
            #pragma unroll
            for (int i = 0; i < 8; i++) qf[qt][i] = f2bf(bf2f(raw[i]) * SCALE_L2E);
        }
    }

    f32x4 z4 = {0.f, 0.f, 0.f, 0.f};
    f32x4 oacc[2][4] = {{z4, z4, z4, z4}, {z4, z4, z4, z4}};

    const short* kbase = kpack + (((size_t)bh) << 10) * 32;
    const short* vbase = v2t + (size_t)bh * 48 * LL;
    unsigned* pw = p_lds[wave];
    int srow = tid >> 1, shalf = tid & 1;     // K staging: key, 16-short half

    for (int c0 = 0; c0 < LL; c0 += 128) {
        __syncthreads();   // protect previous chunk's LDS reads
        // K: 128 keys x 32 shorts (pad cols 32..39 unread garbage)
        *(short8*)&k_lds[srow * 40 + shalf * 16] =
            *(const short8*)&kbase[(size_t)(c0 + srow) * 32 + shalf * 16];
        *(short8*)&k_lds[srow * 40 + shalf * 16 + 8] =
            *(const short8*)&kbase[(size_t)(c0 + srow) * 32 + shalf * 16 + 8];
        // V: 48 rows x 128 shorts = 6144 shorts = 3 x 256 x short8
        #pragma unroll
        for (int p = 0; p < 3; p++) {
            int i2 = p * 256 + tid;
            int f = i2 >> 4, sg = i2 & 15;
            *(short8*)&vT_lds[f * 136 + sg * 8] =
                *(const short8*)&vbase[(size_t)f * LL + c0 + sg * 8];
        }
        __syncthreads();

        // S^T tiles (rows=keys, cols=queries) -> P packed b64 into p_lds[q][key]
        #pragma unroll
        for (int t = 0; t < 8; t++) {
            short8 kf = *(short8*)&k_lds[(t * 16 + l16) * 40 + quad * 8];
            #pragma unroll
            for (int qt = 0; qt < 2; qt++) {
                f32x4 sa = __builtin_amdgcn_mfma_f32_16x16x32_bf16(kf, qf[qt], z4, 0, 0, 0);
                unsigned p01 = pack2(exp2f(sa[0]), exp2f(sa[1]));
                unsigned p23 = pack2(exp2f(sa[2]), exp2f(sa[3]));
                *(uint2*)&pw[(qt * 16 + l16) * 68 + t * 8 + quad * 2] =
                    make_uint2(p01, p23);
            }
        }
        // wave-private p_lds; HW DS ops are in-order per wave.
        asm volatile("" ::: "memory");

        #pragma unroll
        for (int s = 0; s < 4; s++) {
            union { uint4 u; short8 s8; } ca, cb;
            ca.u = *(const uint4*)&pw[l16 * 68 + s * 16 + quad * 4];
            cb.u = *(const uint4*)&pw[(16 + l16) * 68 + s * 16 + quad * 4];
            short8 af0 = ca.s8, af1 = cb.s8;
            #pragma unroll
            for (int nt = 0; nt < 4; nt++) {
                short8 bfv = *(short8*)&vT_lds[(nt * 16 + l16) * 136 + s * 32 + quad * 8];
                oacc[0][nt] = __builtin_amdgcn_mfma_f32_16x16x32_bf16(af0, bfv, oacc[0][nt], 0, 0, 0);
                oacc[1][nt] = __builtin_amdgcn_mfma_f32_16x16x32_bf16(af1, bfv, oacc[1][nt], 0, 0, 0);
            }
        }
    }

    #pragma unroll
    for (int qt = 0; qt < 2; qt++) {
        float linv[4];
        #pragma unroll
        for (int r = 0; r < 4; r++)
            linv[r] = 1.0f / __shfl(oacc[qt][3][r], (lane & 48));
        #pragma unroll
        for (int nt = 0; nt < 3; nt++) {
            int col = h * HD + nt * 16 + l16;
            #pragma unroll
            for (int r = 0; r < 4; r++) {
                int row = q0 + qt * 16 + quad * 4 + r;
                obuf[(size_t)(b * NPIX + row) * C_ + col] = f2bf(oacc[qt][nt][r] * linv[r]);
            }
        }
    }
}

// ---------------------------------------------------------------------------
extern "C" void kernel_launch(void* const* d_in, const int* in_sizes, int n_in,
                              void* d_out, int out_size, void* d_ws, size_t ws_size,
                              hipStream_t stream)
{
    const float* x      = (const float*)d_in[0];
    const float* red_w1 = (const float*)d_in[1];
    const float* red_b1 = (const float*)d_in[2];
    const float* red_w3 = (const float*)d_in[3];
    const float* red_b3 = (const float*)d_in[4];
    const float* red_w5 = (const float*)d_in[5];
    const float* red_b5 = (const float*)d_in[6];
    const float* fus_w  = (const float*)d_in[7];
    const float* fus_b  = (const float*)d_in[8];
    const float* q_w    = (const float*)d_in[9];
    const float* k_w    = (const float*)d_in[10];
    const float* v_w    = (const float*)d_in[11];
    const float* cpe_w  = (const float*)d_in[12];
    const float* cpe_b  = (const float*)d_in[13];
    const float* proj_w = (const float*)d_in[14];
    const float* proj_b = (const float*)d_in[15];
    float* out = (float*)d_out;

    char* ws = (char*)d_ws;
    short* A_fus = (short*)(ws +         0);  // [2048 x 6144] bf16   25.17 MB (reused as obuf)
    short* obuf  = A_fus;
    float* tmpA  = (float*)(ws +  25165824);  // [2,16384,128] fp32   16.78 MB (reused as qbuf)
    short* qbuf  = (short*)(ws +  25165824);
    float* tmpB  = (float*)(ws +  41943040);  // [2,16384,128] fp32   16.78 MB (reused below)
    float* part  = (float*)(ws +  41943040);  // [4][2048 x 192] fp32  6.29 MB
    short* v2t   = (short*)(ws +  48234496);  // [16][48][1024] bf16   1.57 MB
    short* kpack = (short*)(ws +  49807360);  // [16][1024][32] bf16   1.05 MB
    short* Wt    = (short*)(ws +  58720256);  // [6144 x 192] bf16     2.36 MB
    short* Bkv   = (short*)(ws +  61079552);  // [192 x 576] bf16      0.22 MB
    short* qw_b  = (short*)(ws +  61300736);  // [384 x 192] bf16      0.15 MB
    short* pw_b  = (short*)(ws +  61448192);  // [384 x 384] bf16      0.29 MB
    short* xr    = (short*)(ws +  61743104);  // [2048 x 192] bf16     0.79 MB
    short* kvb   = (short*)(ws +  62529536);  // [2048 x 576] bf16     2.36 MB
    short* v2b   = (short*)(ws +  64888832);  // [2048 x 384] bf16     1.57 MB
    (void)in_sizes; (void)n_in; (void)out_size; (void)ws_size;

    dim3 blk(256);
    // reduction dwconv chains (4 pixels/thread; final pass writes patch layout)
    dwconv_k<1,1,C_><<<dim3(4096), blk, 0, stream>>>(x,    0,   nullptr, A_fus, 0,   red_w1, red_b1);
    dwconv_k<0,3,C_><<<dim3(4096), blk, 0, stream>>>(x,    128, tmpA,  nullptr, 0,   red_w3, red_b3);
    dwconv_k<1,3,CG><<<dim3(4096), blk, 0, stream>>>(tmpA, 0,   nullptr, A_fus, 128, red_w3, red_b3);
    dwconv_k<0,5,C_><<<dim3(4096), blk, 0, stream>>>(x,    256, tmpB,  nullptr, 0,   red_w5, red_b5);
    dwconv_k<0,5,CG><<<dim3(4096), blk, 0, stream>>>(tmpB, 0,   tmpA,  nullptr, 0,   red_w5, red_b5);
    dwconv_k<1,5,CG><<<dim3(4096), blk, 0, stream>>>(tmpA, 0,   nullptr, A_fus, 256, red_w5, red_b5);
    // weight prep (fp32 -> bf16)
    prep_k<<<dim3(5904), blk, 0, stream>>>(fus_w, k_w, v_w, q_w, proj_w, Wt, Bkv, qw_b, pw_b);
    // fusion conv as split-K=4 GEMM -> fp32 partials -> reduce + bias + GELU
    gemm_part_k<<<dim3(32, 3, 4), blk, 0, stream>>>(A_fus, Wt, part, 2048, CR, KFUS, KFUS / 4);
    fusred_k<<<dim3(1536), blk, 0, stream>>>(part, fus_b, xr);
    // k|v = xr @ [k_w | v_w]  -> kvb [2048 x 576]
    gemm_k<0,0><<<dim3(32, 9), blk, 0, stream>>>(xr, Bkv, kvb, (const float*)nullptr, 2048, 576, CR);
    // v2 = v + cpe dwconv
    cpe_k<<<dim3(3072), blk, 0, stream>>>(kvb, cpe_w, cpe_b, v2b);
    // layout prep for attention
    transp_k<<<dim3(2304), blk, 0, stream>>>(v2b, kvb, v2t, kpack);
    // q = x @ q_w -> qbuf [32768 x 192]
    gemm_k<1,0><<<dim3(512, 3), blk, 0, stream>>>(x, qw_b, qbuf, (const float*)nullptr, 32768, CR, C_);
    // flash attention -> obuf [32768 x 384]
    attn_k<<<dim3(128, 16), blk, 0, stream>>>(qbuf, kpack, v2t, obuf);
    // projection -> out (fp32)
    gemm_k<0,1><<<dim3(512, 6), blk, 0, stream>>>(obuf, pw_b, out, proj_b, 32768, C_, C_);
}

// Round 9
// 458.185 us; speedup vs baseline: 1.0221x; 1.0221x over previous
//
#include <hip/hip_runtime.h>
#include <math.h>

typedef short short8 __attribute__((ext_vector_type(8)));
typedef float f32x4 __attribute__((ext_vector_type(4)));

#define B_    2
#define HH    128
#define WW    128
#define NPIX  16384     // H*W
#define C_    384
#define CR    192
#define CG    128
#define NH    8
#define DK    24
#define HD    48
#define LL    1024      // 32*32 reduced tokens
#define KFUS  6144      // 16*384
// (hd*0.5)^-0.5 * log2(e)  — folded so P = exp2(S)
#define SCALE_L2E 0.29448889f

__device__ __forceinline__ float bf2f(short h) {
    union { unsigned u; float f; } v; v.u = ((unsigned)(unsigned short)h) << 16; return v.f;
}
__device__ __forceinline__ short f2bf(float f) {          // RNE
    union { float f; unsigned u; } v; v.f = f;
    unsigned r = v.u + 0x7fffu + ((v.u >> 16) & 1u);
    return (short)(unsigned short)(r >> 16);
}
__device__ __forceinline__ short f2bf_fast(float f) {     // round-nearest, ties-away
    union { float f; unsigned u; } v; v.f = f;
    return (short)(unsigned short)((v.u + 0x8000u) >> 16);
}
// pack bf16(a) (low) | bf16(b) (high), ties-away rounding, single v_perm_b32.
// perm(S0,S1,sel): sel byte 0-3 -> S1 byte, 4-7 -> S0 byte. Verified: r8's
// pure-C equivalent passed; this is the 1-op fused form.
__device__ __forceinline__ unsigned pack2(float a, float b) {
    union { float f; unsigned u; } x, y; x.f = a; y.f = b;
    return __builtin_amdgcn_perm(y.u + 0x8000u, x.u + 0x8000u, 0x07060302u);
}

// ---------------------------------------------------------------------------
// Depthwise conv, one 128-channel group, 4 x-pixels per thread (x0 % 4 == 0).
// PATCH=0: fp32 flat out [B,NPIX,128].
// PATCH=1: bf16 im2col patch layout for the 4x4/stride4 conv.
// ---------------------------------------------------------------------------
template<int PATCH, int KS, int STRIDE>
__global__ __launch_bounds__(256) void dwconv_k(
    const float* __restrict__ in, int in_off,
    float* __restrict__ outf, short* __restrict__ outp, int out_coff,
    const float* __restrict__ w, const float* __restrict__ bias)
{
    constexpr int pad = KS / 2;
    constexpr int NV = 4 + KS - 1;
    int idx = blockIdx.x * 256 + threadIdx.x;   // 2*4096*128 total
    int c    = idx & (CG - 1);
    int pix4 = (idx >> 7) & 4095;
    int b    = idx >> 19;
    int y = pix4 >> 5, x0 = (pix4 & 31) << 2;
    float wl[KS * KS];
    #pragma unroll
    for (int i = 0; i < KS * KS; i++) wl[i] = w[c * KS * KS + i];
    float bv = bias[c];
    float acc[4] = {bv, bv, bv, bv};
    #pragma unroll
    for (int ky = 0; ky < KS; ky++) {
        int yy = y + ky - pad;
        if ((unsigned)yy >= HH) continue;
        const float* rowp = &in[(size_t)(b * NPIX + yy * WW) * STRIDE + in_off + c];
        float v[NV];
        #pragma unroll
        for (int j = 0; j < NV; j++) {
            int xx = x0 + j - pad;
            v[j] = ((unsigned)xx < WW) ? rowp[(size_t)xx * STRIDE] : 0.f;
        }
        #pragma unroll
        for (int kx = 0; kx < KS; kx++)
            #pragma unroll
            for (int o = 0; o < 4; o++)
                acc[o] += v[o + kx] * wl[ky * KS + kx];
    }
    if (!PATCH) {
        float* op = &outf[(size_t)(b * NPIX + y * WW + x0) * CG + c];
        #pragma unroll
        for (int o = 0; o < 4; o++) op[(size_t)o * CG] = acc[o];
    } else {
        int m = b * LL + (y >> 2) * 32 + (x0 >> 2);
        short* op = &outp[(size_t)m * KFUS + ((y & 3) * 4) * C_ + out_coff + c];
        #pragma unroll
        for (int o = 0; o < 4; o++) op[(size_t)o * C_] = f2bf(acc[o]);
    }
}

// ---------------------------------------------------------------------------
// Weight prep (fp32 -> bf16)
// ---------------------------------------------------------------------------
__global__ __launch_bounds__(256) void prep_k(
    const float* __restrict__ fus_w, const float* __restrict__ k_w,
    const float* __restrict__ v_w, const float* __restrict__ q_w,
    const float* __restrict__ proj_w,
    short* __restrict__ Wt, short* __restrict__ Bkv,
    short* __restrict__ qw_b, short* __restrict__ pw_b)
{
    int idx = blockIdx.x * 256 + threadIdx.x;
    const int NW = KFUS * CR;        // 1179648
    if (idx < NW) {
        int k = idx / CR, oc = idx - k * CR;
        int p = k / C_,  ic = k - p * C_;
        Wt[idx] = f2bf(fus_w[(oc * C_ + ic) * 16 + p]);
        return;
    }
    idx -= NW;
    if (idx < CR * 576) {            // 110592
        int k = idx / 576, n = idx - k * 576;
        Bkv[idx] = f2bf((n < CR) ? k_w[k * CR + n] : v_w[k * C_ + (n - CR)]);
        return;
    }
    idx -= CR * 576;
    if (idx < C_ * CR) { qw_b[idx] = f2bf(q_w[idx]); return; }
    idx -= C_ * CR;
    if (idx < C_ * C_) pw_b[idx] = f2bf(proj_w[idx]);
}

// ---------------------------------------------------------------------------
// Generic bf16 MFMA GEMM: C[M,N] = A[M,K] * B[K,N] (+bias)
// AF=1: A fp32 (converted on stage). CF=1: C written fp32.
// ---------------------------------------------------------------------------
template<int AF, int CF>
__global__ __launch_bounds__(256) void gemm_k(
    const void* __restrict__ Av, const short* __restrict__ Bm, void* __restrict__ Cv,
    const float* __restrict__ bias, int M, int N, int K)
{
    __shared__ short a_lds[64 * 40];
    __shared__ short bT_lds[64 * 40];
    int tid = threadIdx.x;
    int lane = tid & 63, wave = tid >> 6, quad = lane >> 4, l16 = lane & 15;
    int bm = blockIdx.x * 64, bn = blockIdx.y * 64;
    int wm = (wave >> 1) * 32, wn = (wave & 1) * 32;
    f32x4 z4 = {0.f, 0.f, 0.f, 0.f};
    f32x4 acc00 = z4, acc01 = z4, acc10 = z4, acc11 = z4;
    int arow = tid >> 2, aseg = tid & 3;
    int bk = tid >> 3, bnseg = tid & 7;

    for (int k0 = 0; k0 < K; k0 += 32) {
        __syncthreads();
        if (AF) {
            const float* Af = (const float*)Av;
            const float4* p = (const float4*)&Af[(size_t)(bm + arow) * K + k0 + aseg * 8];
            float4 f0 = p[0], f1 = p[1];
            short8 av;
            av[0] = f2bf_fast(f0.x); av[1] = f2bf_fast(f0.y);
            av[2] = f2bf_fast(f0.z); av[3] = f2bf_fast(f0.w);
            av[4] = f2bf_fast(f1.x); av[5] = f2bf_fast(f1.y);
            av[6] = f2bf_fast(f1.z); av[7] = f2bf_fast(f1.w);
            *(short8*)&a_lds[arow * 40 + aseg * 8] = av;
        } else {
            const short* Ab = (const short*)Av;
            *(short8*)&a_lds[arow * 40 + aseg * 8] =
                *(const short8*)&Ab[(size_t)(bm + arow) * K + k0 + aseg * 8];
        }
        short8 bv = *(const short8*)&Bm[(size_t)(k0 + bk) * N + bn + bnseg * 8];
        #pragma unroll
        for (int i = 0; i < 8; i++) bT_lds[(bnseg * 8 + i) * 40 + bk] = bv[i];
        __syncthreads();
        short8 a0 = *(short8*)&a_lds[(wm + l16) * 40 + quad * 8];
        short8 a1 = *(short8*)&a_lds[(wm + 16 + l16) * 40 + quad * 8];
        short8 b0 = *(short8*)&bT_lds[(wn + l16) * 40 + quad * 8];
        short8 b1 = *(short8*)&bT_lds[(wn + 16 + l16) * 40 + quad * 8];
        acc00 = __builtin_amdgcn_mfma_f32_16x16x32_bf16(a0, b0, acc00, 0, 0, 0);
        acc01 = __builtin_amdgcn_mfma_f32_16x16x32_bf16(a0, b1, acc01, 0, 0, 0);
        acc10 = __builtin_amdgcn_mfma_f32_16x16x32_bf16(a1, b0, acc10, 0, 0, 0);
        acc11 = __builtin_amdgcn_mfma_f32_16x16x32_bf16(a1, b1, acc11, 0, 0, 0);
    }
    f32x4 accs[2][2] = {{acc00, acc01}, {acc10, acc11}};
    #pragma unroll
    for (int mt = 0; mt < 2; mt++)
      #pragma unroll
      for (int nt = 0; nt < 2; nt++) {
        int col = bn + wn + nt * 16 + l16;
        float bvv = bias ? bias[col] : 0.f;
        #pragma unroll
        for (int r = 0; r < 4; r++) {
            int row = bm + wm + mt * 16 + quad * 4 + r;
            float v = accs[mt][nt][r] + bvv;
            if (CF) ((float*)Cv)[(size_t)row * N + col] = v;
            else    ((short*)Cv)[(size_t)row * N + col] = f2bf(v);
        }
      }
}

// ---------------------------------------------------------------------------
// Split-K GEMM for the fusion conv: fp32 partials per z-slice.
// ---------------------------------------------------------------------------
__global__ __launch_bounds__(256) void gemm_part_k(
    const short* __restrict__ A, const short* __restrict__ Bm,
    float* __restrict__ Cpart, int M, int N, int K, int kchunk)
{
    __shared__ short a_lds[64 * 40];
    __shared__ short bT_lds[64 * 40];
    int tid = threadIdx.x;
    int lane = tid & 63, wave = tid >> 6, quad = lane >> 4, l16 = lane & 15;
    int bm = blockIdx.x * 64, bn = blockIdx.y * 64;
    int kbeg = blockIdx.z * kchunk, kend = kbeg + kchunk;
    int wm = (wave >> 1) * 32, wn = (wave & 1) * 32;
    f32x4 z4 = {0.f, 0.f, 0.f, 0.f};
    f32x4 acc00 = z4, acc01 = z4, acc10 = z4, acc11 = z4;
    int arow = tid >> 2, aseg = tid & 3;
    int bk = tid >> 3, bnseg = tid & 7;

    for (int k0 = kbeg; k0 < kend; k0 += 32) {
        __syncthreads();
        *(short8*)&a_lds[arow * 40 + aseg * 8] =
            *(const short8*)&A[(size_t)(bm + arow) * K + k0 + aseg * 8];
        short8 bv = *(const short8*)&Bm[(size_t)(k0 + bk) * N + bn + bnseg * 8];
        #pragma unroll
        for (int i = 0; i < 8; i++) bT_lds[(bnseg * 8 + i) * 40 + bk] = bv[i];
        __syncthreads();
        short8 a0 = *(short8*)&a_lds[(wm + l16) * 40 + quad * 8];
        short8 a1 = *(short8*)&a_lds[(wm + 16 + l16) * 40 + quad * 8];
        short8 b0 = *(short8*)&bT_lds[(wn + l16) * 40 + quad * 8];
        short8 b1 = *(short8*)&bT_lds[(wn + 16 + l16) * 40 + quad * 8];
        acc00 = __builtin_amdgcn_mfma_f32_16x16x32_bf16(a0, b0, acc00, 0, 0, 0);
        acc01 = __builtin_amdgcn_mfma_f32_16x16x32_bf16(a0, b1, acc01, 0, 0, 0);
        acc10 = __builtin_amdgcn_mfma_f32_16x16x32_bf16(a1, b0, acc10, 0, 0, 0);
        acc11 = __builtin_amdgcn_mfma_f32_16x16x32_bf16(a1, b1, acc11, 0, 0, 0);
    }
    float* Cs = Cpart + (size_t)blockIdx.z * M * N;
    f32x4 accs[2][2] = {{acc00, acc01}, {acc10, acc11}};
    #pragma unroll
    for (int mt = 0; mt < 2; mt++)
      #pragma unroll
      for (int nt = 0; nt < 2; nt++) {
        int col = bn + wn + nt * 16 + l16;
        #pragma unroll
        for (int r = 0; r < 4; r++) {
            int row = bm + wm + mt * 16 + quad * 4 + r;
            Cs[(size_t)row * N + col] = accs[mt][nt][r];
        }
      }
}

// Reduce 4 split-K partials + bias + exact GELU -> bf16 xr [2048 x 192]
__global__ __launch_bounds__(256) void fusred_k(
    const float* __restrict__ part, const float* __restrict__ bias,
    short* __restrict__ xr)
{
    const int MN = 2048 * CR;
    int idx = blockIdx.x * 256 + threadIdx.x;
    float v = part[idx] + part[idx + MN] + part[idx + 2 * MN] + part[idx + 3 * MN]
            + bias[idx % CR];
    v = 0.5f * v * (1.f + erff(v * 0.70710678118f));
    xr[idx] = f2bf(v);
}

// ---------------------------------------------------------------------------
// CPE: v2[b,l,c] = v[b,l,c] + dwconv3x3(v as [B,C,32,32])[b,c,l] + cpe_b[c]
// ---------------------------------------------------------------------------
__global__ __launch_bounds__(256) void cpe_k(
    const short* __restrict__ kv, const float* __restrict__ cw,
    const float* __restrict__ cb, short* __restrict__ v2)
{
    int idx = blockIdx.x * 256 + threadIdx.x;   // 2*1024*384
    int c = idx % C_;
    int t = idx / C_;
    int l = t & (LL - 1);
    int b = t >> 10;
    int y = l >> 5, x = l & 31;
    const short* vp = kv + CR;
    float acc = bf2f(vp[(size_t)(b * LL + l) * 576 + c]) + cb[c];
    #pragma unroll
    for (int ky = 0; ky < 3; ky++) {
        int yy = y + ky - 1; if ((unsigned)yy >= 32) continue;
        #pragma unroll
        for (int kx = 0; kx < 3; kx++) {
            int xx = x + kx - 1; if ((unsigned)xx >= 32) continue;
            acc += bf2f(vp[(size_t)(b * LL + yy * 32 + xx) * 576 + c])
                 * cw[c * 9 + ky * 3 + kx];
        }
    }
    v2[(size_t)(b * LL + l) * C_ + c] = f2bf(acc);
}

// ---------------------------------------------------------------------------
// Build attention-friendly layouts:
//   v2t[bh][f 0..47][l 0..1023]  (transposed V, per head)
//   kpack[bh][l][j 0..31]        (K zero-padded dk24->32)
// ---------------------------------------------------------------------------
__global__ __launch_bounds__(256) void transp_k(
    const short* __restrict__ v2b, const short* __restrict__ kvb,
    short* __restrict__ v2t, short* __restrict__ kpack)
{
    int tid = threadIdx.x;
    if (blockIdx.x < 256) {
        __shared__ short t_lds[64 * 49];
        int bh = blockIdx.x >> 4, b = bh >> 3, h = bh & 7;
        int l0 = (blockIdx.x & 15) << 6;
        for (int i = tid; i < 64 * 48; i += 256) {
            int dl = i / 48, f = i - dl * 48;
            t_lds[dl * 49 + f] = v2b[(size_t)(b * LL + l0 + dl) * C_ + h * HD + f];
        }
        __syncthreads();
        for (int i = tid; i < 64 * 48; i += 256) {
            int f = i >> 6, dl = i & 63;
            v2t[((size_t)bh * 48 + f) * LL + l0 + dl] = t_lds[dl * 49 + f];
        }
    } else {
        int gid = (blockIdx.x - 256) * 256 + tid;   // 16*1024*32
        int j = gid & 31, t = gid >> 5;
        int l = t & (LL - 1), bh = t >> 10;
        int b = bh >> 3, h = bh & 7;
        kpack[gid] = (j < 24) ? kvb[(size_t)(b * LL + l) * 576 + h * DK + j] : (short)0;
    }
}

// ---------------------------------------------------------------------------
// Flash attention v5: barrier-free. K and V fragments load straight from
// global (kpack/v2t, L2-resident); LDS holds only the per-wave P transpose
// buffer (34.8 KB -> 4 blocks/CU). Row sums accumulated in VALU from the
// fp32 exp values (lane's S^T row = keys of one query). No-max exp2 softmax.
// ---------------------------------------------------------------------------
__global__ __launch_bounds__(256, 4) void attn_k(
    const short* __restrict__ qbuf, const short* __restrict__ kpack,
    const short* __restrict__ v2t, short* __restrict__ obuf)
{
    __shared__ unsigned p_lds[4][32 * 68];   // per-wave [query][key/2] bf16x2
    int tid = threadIdx.x;
    int lane = tid & 63, wave = tid >> 6, quad = lane >> 4, l16 = lane & 15;
    int bh = blockIdx.y, b = bh >> 3, h = bh & 7;
    int q0 = blockIdx.x * 128 + wave * 32;

    // Q fragments (2 x 16 queries), pre-scaled by scale*log2(e); k>=24 zero.
    short8 qf[2];
    #pragma unroll
    for (int qt = 0; qt < 2; qt++) {
        short8 z = {0, 0, 0, 0, 0, 0, 0, 0};
        qf[qt] = z;
        if (quad < 3) {
            short8 raw = *(const short8*)&qbuf[(size_t)(b * NPIX + q0 + qt * 16 + l16) * CR + h * DK + quad * 8];
            #pragma unroll
            for (int i = 0; i < 8; i++) qf[qt][i] = f2bf(bf2f(raw[i]) * SCALE_L2E);
        }
    }

    f32x4 z4 = {0.f, 0.f, 0.f, 0.f};
    f32x4 oacc[2][3] = {{z4, z4, z4}, {z4, z4, z4}};
    float rs[2] = {0.f, 0.f};       // per-lane partial softmax denominators

    const short* kbase = kpack + (((size_t)bh) << 10) * 32;
    const short* vbase = v2t + (size_t)bh * 48 * LL;
    unsigned* pw = p_lds[wave];

    for (int c0 = 0; c0 < LL; c0 += 128) {
        // S^T tiles (rows=keys, cols=queries); K frags straight from global.
        #pragma unroll
        for (int t = 0; t < 8; t++) {
            short8 kf = *(const short8*)&kbase[(size_t)(c0 + t * 16 + l16) * 32 + quad * 8];
            #pragma unroll
            for (int qt = 0; qt < 2; qt++) {
                f32x4 sa = __builtin_amdgcn_mfma_f32_16x16x32_bf16(kf, qf[qt], z4, 0, 0, 0);
                float e0 = exp2f(sa[0]), e1 = exp2f(sa[1]);
                float e2 = exp2f(sa[2]), e3 = exp2f(sa[3]);
                rs[qt] += (e0 + e1) + (e2 + e3);
                *(uint2*)&pw[(qt * 16 + l16) * 68 + t * 8 + quad * 2] =
                    make_uint2(pack2(e0, e1), pack2(e2, e3));
            }
        }
        // wave-private p_lds; HW DS ops in-order per wave, fence stops compiler
        asm volatile("" ::: "memory");

        // PV: P from LDS (A-frags), V frags straight from global.
        #pragma unroll
        for (int s = 0; s < 4; s++) {
            union { uint4 u; short8 s8; } ca, cb;
            ca.u = *(const uint4*)&pw[l16 * 68 + s * 16 + quad * 4];
            cb.u = *(const uint4*)&pw[(16 + l16) * 68 + s * 16 + quad * 4];
            #pragma unroll
            for (int nt = 0; nt < 3; nt++) {
                short8 bfv = *(const short8*)&vbase[(size_t)(nt * 16 + l16) * LL + c0 + s * 32 + quad * 8];
                oacc[0][nt] = __builtin_amdgcn_mfma_f32_16x16x32_bf16(ca.s8, bfv, oacc[0][nt], 0, 0, 0);
                oacc[1][nt] = __builtin_amdgcn_mfma_f32_16x16x32_bf16(cb.s8, bfv, oacc[1][nt], 0, 0, 0);
            }
        }
        asm volatile("" ::: "memory");
    }

    #pragma unroll
    for (int qt = 0; qt < 2; qt++) {
        // full denominator for this lane's query (l16): reduce across quads
        float s = rs[qt];
        s += __shfl_xor(s, 16);
        s += __shfl_xor(s, 32);
        // oacc rows are queries quad*4+r; fetch their denominators
        float linv[4];
        #pragma unroll
        for (int r = 0; r < 4; r++)
            linv[r] = 1.0f / __shfl(s, quad * 4 + r);
        #pragma unroll
        for (int nt = 0; nt < 3; nt++) {
            int col = h * HD + nt * 16 + l16;
            #pragma unroll
            for (int r = 0; r < 4; r++) {
                int row = q0 + qt * 16 + quad * 4 + r;
                obuf[(size_t)(b * NPIX + row) * C_ + col] = f2bf(oacc[qt][nt][r] * linv[r]);
            }
        }
    }
}

// ---------------------------------------------------------------------------
extern "C" void kernel_launch(void* const* d_in, const int* in_sizes, int n_in,
                              void* d_out, int out_size, void* d_ws, size_t ws_size,
                              hipStream_t stream)
{
    const float* x      = (const float*)d_in[0];
    const float* red_w1 = (const float*)d_in[1];
    const float* red_b1 = (const float*)d_in[2];
    const float* red_w3 = (const float*)d_in[3];
    const float* red_b3 = (const float*)d_in[4];
    const float* red_w5 = (const float*)d_in[5];
    const float* red_b5 = (const float*)d_in[6];
    const float* fus_w  = (const float*)d_in[7];
    const float* fus_b  = (const float*)d_in[8];
    const float* q_w    = (const float*)d_in[9];
    const float* k_w    = (const float*)d_in[10];
    const float* v_w    = (const float*)d_in[11];
    const float* cpe_w  = (const float*)d_in[12];
    const float* cpe_b  = (const float*)d_in[13];
    const float* proj_w = (const float*)d_in[14];
    const float* proj_b = (const float*)d_in[15];
    float* out = (float*)d_out;

    char* ws = (char*)d_ws;
    short* A_fus = (short*)(ws +         0);  // [2048 x 6144] bf16   25.17 MB (reused as obuf)
    short* obuf  = A_fus;
    float* tmpA  = (float*)(ws +  25165824);  // [2,16384,128] fp32   16.78 MB (reused as qbuf)
    short* qbuf  = (short*)(ws +  25165824);
    float* tmpB  = (float*)(ws +  41943040);  // [2,16384,128] fp32   16.78 MB (reused below)
    float* part  = (float*)(ws +  41943040);  // [4][2048 x 192] fp32  6.29 MB
    short* v2t   = (short*)(ws +  48234496);  // [16][48][1024] bf16   1.57 MB
    short* kpack = (short*)(ws +  49807360);  // [16][1024][32] bf16   1.05 MB
    short* Wt    = (short*)(ws +  58720256);  // [6144 x 192] bf16     2.36 MB
    short* Bkv   = (short*)(ws +  61079552);  // [192 x 576] bf16      0.22 MB
    short* qw_b  = (short*)(ws +  61300736);  // [384 x 192] bf16      0.15 MB
    short* pw_b  = (short*)(ws +  61448192);  // [384 x 384] bf16      0.29 MB
    short* xr    = (short*)(ws +  61743104);  // [2048 x 192] bf16     0.79 MB
    short* kvb   = (short*)(ws +  62529536);  // [2048 x 576] bf16     2.36 MB
    short* v2b   = (short*)(ws +  64888832);  // [2048 x 384] bf16     1.57 MB
    (void)in_sizes; (void)n_in; (void)out_size; (void)ws_size;

    dim3 blk(256);
    // reduction dwconv chains (4 pixels/thread; final pass writes patch layout)
    dwconv_k<1,1,C_><<<dim3(4096), blk, 0, stream>>>(x,    0,   nullptr, A_fus, 0,   red_w1, red_b1);
    dwconv_k<0,3,C_><<<dim3(4096), blk, 0, stream>>>(x,    128, tmpA,  nullptr, 0,   red_w3, red_b3);
    dwconv_k<1,3,CG><<<dim3(4096), blk, 0, stream>>>(tmpA, 0,   nullptr, A_fus, 128, red_w3, red_b3);
    dwconv_k<0,5,C_><<<dim3(4096), blk, 0, stream>>>(x,    256, tmpB,  nullptr, 0,   red_w5, red_b5);
    dwconv_k<0,5,CG><<<dim3(4096), blk, 0, stream>>>(tmpB, 0,   tmpA,  nullptr, 0,   red_w5, red_b5);
    dwconv_k<1,5,CG><<<dim3(4096), blk, 0, stream>>>(tmpA, 0,   nullptr, A_fus, 256, red_w5, red_b5);
    // weight prep (fp32 -> bf16)
    prep_k<<<dim3(5904), blk, 0, stream>>>(fus_w, k_w, v_w, q_w, proj_w, Wt, Bkv, qw_b, pw_b);
    // fusion conv as split-K=4 GEMM -> fp32 partials -> reduce + bias + GELU
    gemm_part_k<<<dim3(32, 3, 4), blk, 0, stream>>>(A_fus, Wt, part, 2048, CR, KFUS, KFUS / 4);
    fusred_k<<<dim3(1536), blk, 0, stream>>>(part, fus_b, xr);
    // k|v = xr @ [k_w | v_w]  -> kvb [2048 x 576]
    gemm_k<0,0><<<dim3(32, 9), blk, 0, stream>>>(xr, Bkv, kvb, (const float*)nullptr, 2048, 576, CR);
    // v2 = v + cpe dwconv
    cpe_k<<<dim3(3072), blk, 0, stream>>>(kvb, cpe_w, cpe_b, v2b);
    // layout prep for attention
    transp_k<<<dim3(2304), blk, 0, stream>>>(v2b, kvb, v2t, kpack);
    // q = x @ q_w -> qbuf [32768 x 192]
    gemm_k<1,0><<<dim3(512, 3), blk, 0, stream>>>(x, qw_b, qbuf, (const float*)nullptr, 32768, CR, C_);
    // flash attention -> obuf [32768 x 384]
    attn_k<<<dim3(128, 16), blk, 0, stream>>>(qbuf, kpack, v2t, obuf);
    // projection -> out (fp32)
    gemm_k<0,1><<<dim3(512, 6), blk, 0, stream>>>(obuf, pw_b, out, proj_b, 32768, C_, C_);
}